// Round 1
// 1179.419 us; speedup vs baseline: 1.2122x; 1.2122x over previous
//
#include <hip/hip_runtime.h>
#include <hip/hip_bf16.h>

#define S_LEN 2048
#define DMODEL 1024
#define NH 16
#define DHEAD 64
#define M_TOT 4096  // B*S

typedef __attribute__((ext_vector_type(8))) short bf16x8;
typedef __attribute__((ext_vector_type(4))) float f32x4;

__device__ __forceinline__ short f2bf(float x) {
  __hip_bfloat16 h = __float2bfloat16(x);
  short s; __builtin_memcpy(&s, &h, 2); return s;
}
__device__ __forceinline__ float bf2f(short s) {
  __hip_bfloat16 h; __builtin_memcpy(&h, &s, 2);
  return __bfloat162float(h);
}

// async global->LDS copy, 16B per lane (global_load_lds_dwordx4)
__device__ __forceinline__ void async16(const short* g, short* l) {
  __builtin_amdgcn_global_load_lds(
      (const __attribute__((address_space(1))) unsigned int*)g,
      (__attribute__((address_space(3))) unsigned int*)l, 16, 0, 0);
}

// stage a 128x32 bf16 tile from row-major [*][DMODEL] src into linear LDS
// 256 threads: thread t covers row t/4 (+64), cols (t%4)*8..+8
__device__ __forceinline__ void stage_tile(const short* __restrict__ src, int row0,
                                           int k0, short* lds, int t) {
  const int r = t >> 2, c = (t & 3) << 3;
  async16(src + (size_t)(row0 + r) * DMODEL + k0 + c, lds + t * 8);
  async16(src + (size_t)(row0 + 64 + r) * DMODEL + k0 + c, lds + 2048 + t * 8);
}

// ---------------- elementwise: fp32 -> (hi, lo) bf16 split ----------------
__global__ void split_cvt(const float* __restrict__ src, short* __restrict__ hi,
                          short* __restrict__ lo, int n4) {
  int i = blockIdx.x * blockDim.x + threadIdx.x;
  if (i >= n4) return;
  float4 x = reinterpret_cast<const float4*>(src)[i];
  short4 h, l;
  h.x = f2bf(x.x); h.y = f2bf(x.y); h.z = f2bf(x.z); h.w = f2bf(x.w);
  l.x = f2bf(x.x - bf2f(h.x)); l.y = f2bf(x.y - bf2f(h.y));
  l.z = f2bf(x.z - bf2f(h.z)); l.w = f2bf(x.w - bf2f(h.w));
  reinterpret_cast<short4*>(hi)[i] = h;
  reinterpret_cast<short4*>(lo)[i] = l;
}

// ---------------- W (k x n fp32) -> hiT/loT (n x k bf16) ----------------
__global__ void transpose_split_w(const float* __restrict__ W,
                                  short* __restrict__ hiT, short* __restrict__ loT) {
  __shared__ float t[32][33];
  int tx = threadIdx.x;              // 0..31
  int kb = blockIdx.y * 32;          // k block (rows of W)
  int nb = blockIdx.x * 32;          // n block (cols of W)
  for (int ty = threadIdx.y; ty < 32; ty += 8)
    t[ty][tx] = W[(size_t)(kb + ty) * DMODEL + nb + tx];
  __syncthreads();
  for (int ty = threadIdx.y; ty < 32; ty += 8) {
    float x = t[tx][ty];  // = W[kb+tx][nb+ty]
    short hv = f2bf(x);
    hiT[(size_t)(nb + ty) * DMODEL + kb + tx] = hv;
    loT[(size_t)(nb + ty) * DMODEL + kb + tx] = f2bf(x - bf2f(hv));
  }
}

// ---------------- QKV projection GEMM (split bf16, fused 3-term MFMA) ----
// C(4096x1024) = A @ W + b ; A split hi/lo [m][k], W split [n][k] (transposed).
// LDS-staged 128x128 tile, BK=32, one K-pass with 3 MFMAs per fragment pair:
//   C = Ah@Bh + Ah@Bl + Al@Bh   (Al@Bl term ~2^-16, dropped)
// which: 0=Q -> qh [b][h][s][d], 1=K -> kh [b][h][s][d], 2=V -> vT [b][h][d][s]
__launch_bounds__(256)
__global__ void proj_gemm(
    const short* __restrict__ qa_hi, const short* __restrict__ qa_lo,
    const short* __restrict__ ka_hi, const short* __restrict__ ka_lo,
    const short* __restrict__ va_hi, const short* __restrict__ va_lo,
    const short* __restrict__ wq_hiT, const short* __restrict__ wq_loT,
    const short* __restrict__ wk_hiT, const short* __restrict__ wk_loT,
    const short* __restrict__ wv_hiT, const short* __restrict__ wv_loT,
    const float* __restrict__ bq, const float* __restrict__ bk,
    const float* __restrict__ bv,
    short* __restrict__ qh, short* __restrict__ kh, short* __restrict__ vT) {
  const int which = blockIdx.z;
  const short* Ahi = (which == 0) ? qa_hi : (which == 1) ? ka_hi : va_hi;
  const short* Alo = (which == 0) ? qa_lo : (which == 1) ? ka_lo : va_lo;
  const short* Bhi = (which == 0) ? wq_hiT : (which == 1) ? wk_hiT : wv_hiT;
  const short* Blo = (which == 0) ? wq_loT : (which == 1) ? wk_loT : wv_loT;
  const float* bias = (which == 0) ? bq : (which == 1) ? bk : bv;

  const int m0 = blockIdx.y * 128, n0 = blockIdx.x * 128;
  const int t = threadIdx.x;
  const int lane = t & 63, wave = t >> 6;
  const int wm = (wave >> 1) * 64, wn = (wave & 1) * 64;
  const int lm = lane & 15, quad = lane >> 4;

  __shared__ short sAh[128 * 32], sAl[128 * 32];
  __shared__ short sBh[128 * 32], sBl[128 * 32];

  f32x4 acc[4][4];
#pragma unroll
  for (int i = 0; i < 4; i++)
#pragma unroll
    for (int j = 0; j < 4; j++) acc[i][j] = (f32x4){0.f, 0.f, 0.f, 0.f};

  for (int k0 = 0; k0 < DMODEL; k0 += 32) {
    stage_tile(Ahi, m0, k0, sAh, t);
    stage_tile(Alo, m0, k0, sAl, t);
    stage_tile(Bhi, n0, k0, sBh, t);
    stage_tile(Blo, n0, k0, sBl, t);
    __syncthreads();  // drains vmcnt -> LDS tiles valid

    bf16x8 ah[4], al[4], bh[4], bl[4];
#pragma unroll
    for (int i = 0; i < 4; i++) {
      ah[i] = *reinterpret_cast<const bf16x8*>(sAh + (wm + i * 16 + lm) * 32 + quad * 8);
      al[i] = *reinterpret_cast<const bf16x8*>(sAl + (wm + i * 16 + lm) * 32 + quad * 8);
    }
#pragma unroll
    for (int j = 0; j < 4; j++) {
      bh[j] = *reinterpret_cast<const bf16x8*>(sBh + (wn + j * 16 + lm) * 32 + quad * 8);
      bl[j] = *reinterpret_cast<const bf16x8*>(sBl + (wn + j * 16 + lm) * 32 + quad * 8);
    }
#pragma unroll
    for (int i = 0; i < 4; i++)
#pragma unroll
      for (int j = 0; j < 4; j++) {
        acc[i][j] = __builtin_amdgcn_mfma_f32_16x16x32_bf16(ah[i], bh[j], acc[i][j], 0, 0, 0);
        acc[i][j] = __builtin_amdgcn_mfma_f32_16x16x32_bf16(ah[i], bl[j], acc[i][j], 0, 0, 0);
        acc[i][j] = __builtin_amdgcn_mfma_f32_16x16x32_bf16(al[i], bh[j], acc[i][j], 0, 0, 0);
      }
    __syncthreads();  // protect LDS before next stage overwrites
  }

#pragma unroll
  for (int j = 0; j < 4; j++) {
    const int col = n0 + wn + j * 16 + lm;
    const float bb = bias[col];
    const int hh = col >> 6, dd = col & 63;
#pragma unroll
    for (int i = 0; i < 4; i++) {
#pragma unroll
      for (int r = 0; r < 4; r++) {
        const int row = m0 + wm + i * 16 + quad * 4 + r;
        const int bidx = row >> 11, ss = row & 2047;
        const float v = acc[i][j][r] + bb;
        if (which < 2) {
          short* dst = (which == 0) ? qh : kh;
          dst[(((size_t)(bidx * NH + hh) * S_LEN) + ss) * DHEAD + dd] = f2bf(v);
        } else {
          vT[(((size_t)(bidx * NH + hh) * DHEAD) + dd) * S_LEN + ss] = f2bf(v);
        }
      }
    }
  }
}

// ---------------- scores -> e = exp(s*scale + mask) + row partial sums ----
__launch_bounds__(256)
__global__ void score_exp(const short* __restrict__ qh, const short* __restrict__ kh,
                          const float* __restrict__ mask,
                          float* __restrict__ wout, float* __restrict__ rsum) {
  const int bh = blockIdx.z;
  const int m0 = blockIdx.y * 128, n0 = blockIdx.x * 128;
  const int lane = threadIdx.x & 63, wave = threadIdx.x >> 6;
  const int wm = (wave >> 1) * 64, wn = (wave & 1) * 64;
  const int lm = lane & 15, quad = lane >> 4;
  const short* qb = qh + (size_t)bh * S_LEN * DHEAD;
  const short* kb = kh + (size_t)bh * S_LEN * DHEAD;

  f32x4 acc[4][4];
#pragma unroll
  for (int i = 0; i < 4; i++)
#pragma unroll
    for (int j = 0; j < 4; j++) acc[i][j] = (f32x4){0.f, 0.f, 0.f, 0.f};

#pragma unroll
  for (int k0 = 0; k0 < DHEAD; k0 += 32) {
    bf16x8 a[4], b[4];
#pragma unroll
    for (int i = 0; i < 4; i++)
      a[i] = *reinterpret_cast<const bf16x8*>(qb + (size_t)(m0 + wm + i * 16 + lm) * DHEAD + k0 + quad * 8);
#pragma unroll
    for (int j = 0; j < 4; j++)
      b[j] = *reinterpret_cast<const bf16x8*>(kb + (size_t)(n0 + wn + j * 16 + lm) * DHEAD + k0 + quad * 8);
#pragma unroll
    for (int i = 0; i < 4; i++)
#pragma unroll
      for (int j = 0; j < 4; j++)
        acc[i][j] = __builtin_amdgcn_mfma_f32_16x16x32_bf16(a[i], b[j], acc[i][j], 0, 0, 0);
  }

  const int b_ = bh >> 4;
  float msk[4];
#pragma unroll
  for (int j = 0; j < 4; j++)
    msk[j] = mask[(size_t)b_ * S_LEN + n0 + wn + j * 16 + lm] * -1e9f;

  float* wb = wout + (size_t)bh * S_LEN * S_LEN;
  float se[4][4];
#pragma unroll
  for (int i = 0; i < 4; i++)
#pragma unroll
    for (int r = 0; r < 4; r++) se[i][r] = 0.f;

#pragma unroll
  for (int i = 0; i < 4; i++) {
#pragma unroll
    for (int j = 0; j < 4; j++) {
#pragma unroll
      for (int r = 0; r < 4; r++) {
        const int row = m0 + wm + i * 16 + quad * 4 + r;
        const int col = n0 + wn + j * 16 + lm;
        float e = __expf(acc[i][j][r] * 0.125f + msk[j]);
        wb[(size_t)row * S_LEN + col] = e;
        se[i][r] += e;
      }
    }
  }
#pragma unroll
  for (int i = 0; i < 4; i++) {
#pragma unroll
    for (int r = 0; r < 4; r++) {
      float v = se[i][r];
      v += __shfl_xor(v, 1); v += __shfl_xor(v, 2);
      v += __shfl_xor(v, 4); v += __shfl_xor(v, 8);
      if (lm == 0)
        atomicAdd(&rsum[(size_t)bh * S_LEN + m0 + wm + i * 16 + quad * 4 + r], v);
    }
  }
}

// ------- PV: normalize e -> weights (write back) and ctx = W @ V ---------
__launch_bounds__(256)
__global__ void pv_norm(float* __restrict__ wio, const short* __restrict__ vT,
                        const float* __restrict__ rsum, short* __restrict__ ctxB) {
  const int bh = blockIdx.y;
  const int mt = blockIdx.x;
  const int lane = threadIdx.x & 63, wave = threadIdx.x >> 6;
  const int lm = lane & 15, quad = lane >> 4;
  const int mbase = mt * 128 + wave * 32;  // each wave owns 32 rows
  float* wb = wio + (size_t)bh * S_LEN * S_LEN;
  const short* vb = vT + (size_t)bh * DHEAD * S_LEN;

  float rinv[2];
#pragma unroll
  for (int i = 0; i < 2; i++)
    rinv[i] = 1.0f / rsum[(size_t)bh * S_LEN + mbase + i * 16 + lm];

  f32x4 acc[2][4];
#pragma unroll
  for (int i = 0; i < 2; i++)
#pragma unroll
    for (int j = 0; j < 4; j++) acc[i][j] = (f32x4){0.f, 0.f, 0.f, 0.f};

  for (int k0 = 0; k0 < S_LEN; k0 += 32) {
    bf16x8 a[2];
#pragma unroll
    for (int i = 0; i < 2; i++) {
      float4* p = reinterpret_cast<float4*>(wb + (size_t)(mbase + i * 16 + lm) * S_LEN + k0 + quad * 8);
      float4 x0 = p[0], x1 = p[1];
      x0.x *= rinv[i]; x0.y *= rinv[i]; x0.z *= rinv[i]; x0.w *= rinv[i];
      x1.x *= rinv[i]; x1.y *= rinv[i]; x1.z *= rinv[i]; x1.w *= rinv[i];
      p[0] = x0; p[1] = x1;  // final normalized weights output
      bf16x8 av;
      av[0] = f2bf(x0.x); av[1] = f2bf(x0.y); av[2] = f2bf(x0.z); av[3] = f2bf(x0.w);
      av[4] = f2bf(x1.x); av[5] = f2bf(x1.y); av[6] = f2bf(x1.z); av[7] = f2bf(x1.w);
      a[i] = av;
    }
    bf16x8 b[4];
#pragma unroll
    for (int j = 0; j < 4; j++)
      b[j] = *reinterpret_cast<const bf16x8*>(vb + (size_t)(j * 16 + lm) * S_LEN + k0 + quad * 8);
#pragma unroll
    for (int i = 0; i < 2; i++)
#pragma unroll
      for (int j = 0; j < 4; j++)
        acc[i][j] = __builtin_amdgcn_mfma_f32_16x16x32_bf16(a[i], b[j], acc[i][j], 0, 0, 0);
  }

  const int b_ = bh >> 4, h = bh & 15;
#pragma unroll
  for (int i = 0; i < 2; i++)
#pragma unroll
    for (int j = 0; j < 4; j++)
#pragma unroll
      for (int r = 0; r < 4; r++) {
        const int ss = mbase + i * 16 + quad * 4 + r;
        const int dd = j * 16 + lm;
        ctxB[((size_t)(b_ * S_LEN + ss)) * DMODEL + h * DHEAD + dd] = f2bf(acc[i][j][r]);
      }
}

// ---------------- output projection: out = ctx @ Wo + bo (bf16 MFMA) -----
// LDS-staged, same 128x128/BK=32 structure as proj_gemm (single hi pass).
__launch_bounds__(256)
__global__ void out_gemm(const short* __restrict__ ctxB, const short* __restrict__ woT,
                         const float* __restrict__ bo, float* __restrict__ out) {
  const int m0 = blockIdx.y * 128, n0 = blockIdx.x * 128;
  const int t = threadIdx.x;
  const int lane = t & 63, wave = t >> 6;
  const int wm = (wave >> 1) * 64, wn = (wave & 1) * 64;
  const int lm = lane & 15, quad = lane >> 4;

  __shared__ short sA[128 * 32], sB[128 * 32];

  f32x4 acc[4][4];
#pragma unroll
  for (int i = 0; i < 4; i++)
#pragma unroll
    for (int j = 0; j < 4; j++) acc[i][j] = (f32x4){0.f, 0.f, 0.f, 0.f};

  for (int k0 = 0; k0 < DMODEL; k0 += 32) {
    stage_tile(ctxB, m0, k0, sA, t);
    stage_tile(woT, n0, k0, sB, t);
    __syncthreads();

    bf16x8 a[4], b[4];
#pragma unroll
    for (int i = 0; i < 4; i++)
      a[i] = *reinterpret_cast<const bf16x8*>(sA + (wm + i * 16 + lm) * 32 + quad * 8);
#pragma unroll
    for (int j = 0; j < 4; j++)
      b[j] = *reinterpret_cast<const bf16x8*>(sB + (wn + j * 16 + lm) * 32 + quad * 8);
#pragma unroll
    for (int i = 0; i < 4; i++)
#pragma unroll
      for (int j = 0; j < 4; j++)
        acc[i][j] = __builtin_amdgcn_mfma_f32_16x16x32_bf16(a[i], b[j], acc[i][j], 0, 0, 0);
    __syncthreads();
  }

#pragma unroll
  for (int j = 0; j < 4; j++) {
    const int col = n0 + wn + j * 16 + lm;
    const float bb = bo[col];
#pragma unroll
    for (int i = 0; i < 4; i++)
#pragma unroll
      for (int r = 0; r < 4; r++) {
        const int row = m0 + wm + i * 16 + quad * 4 + r;
        out[(size_t)row * DMODEL + col] = acc[i][j][r] + bb;
      }
  }
}

extern "C" void kernel_launch(void* const* d_in, const int* in_sizes, int n_in,
                              void* d_out, int out_size, void* d_ws, size_t ws_size,
                              hipStream_t stream) {
  const float* Q = (const float*)d_in[0];
  const float* K = (const float*)d_in[1];
  const float* V = (const float*)d_in[2];
  const float* mask = (const float*)d_in[3];
  const float* Wq = (const float*)d_in[4];
  const float* bq = (const float*)d_in[5];
  const float* Wk = (const float*)d_in[6];
  const float* bk = (const float*)d_in[7];
  const float* Wv = (const float*)d_in[8];
  const float* bv = (const float*)d_in[9];
  const float* Wo = (const float*)d_in[10];
  const float* bo = (const float*)d_in[11];

  float* out0 = (float*)d_out;                                   // (B,S,DM)
  float* weights = (float*)d_out + (size_t)M_TOT * DMODEL;       // (B,H,S,S)

  char* w = (char*)d_ws;
  const size_t MB = 1ull << 20;
  short* qh = (short*)(w + 0 * MB);        // 8 MB  [b][h][s][d] bf16
  short* kh = (short*)(w + 8 * MB);        // 8 MB  [b][h][s][d]
  short* vT = (short*)(w + 16 * MB);       // 8 MB  [b][h][d][s]
  short* ctxB = (short*)(w + 24 * MB);     // 8 MB  [b*s][dm]
  float* rsum = (float*)(w + 32 * MB);     // 256 KB (pad to 1 MB)
  short* wq_hiT = (short*)(w + 33 * MB);
  short* wq_loT = (short*)(w + 35 * MB);
  short* wk_hiT = (short*)(w + 37 * MB);
  short* wk_loT = (short*)(w + 39 * MB);
  short* wv_hiT = (short*)(w + 41 * MB);
  short* wv_loT = (short*)(w + 43 * MB);
  short* wo_hiT = (short*)(w + 45 * MB);
  short* wo_loT = (short*)(w + 47 * MB);   // unused (Wo plain bf16 = hi part)
  short* qa_hi = (short*)(w + 49 * MB);
  short* qa_lo = (short*)(w + 57 * MB);
  short* ka_hi = (short*)(w + 65 * MB);
  short* ka_lo = (short*)(w + 73 * MB);
  short* va_hi = (short*)(w + 81 * MB);
  short* va_lo = (short*)(w + 89 * MB);    // total footprint: 97 MB

  const int n4 = M_TOT * DMODEL / 4;  // 1,048,576
  split_cvt<<<dim3(n4 / 256), 256, 0, stream>>>(Q, qa_hi, qa_lo, n4);
  split_cvt<<<dim3(n4 / 256), 256, 0, stream>>>(K, ka_hi, ka_lo, n4);
  split_cvt<<<dim3(n4 / 256), 256, 0, stream>>>(V, va_hi, va_lo, n4);
  transpose_split_w<<<dim3(32, 32), dim3(32, 8), 0, stream>>>(Wq, wq_hiT, wq_loT);
  transpose_split_w<<<dim3(32, 32), dim3(32, 8), 0, stream>>>(Wk, wk_hiT, wk_loT);
  transpose_split_w<<<dim3(32, 32), dim3(32, 8), 0, stream>>>(Wv, wv_hiT, wv_loT);
  transpose_split_w<<<dim3(32, 32), dim3(32, 8), 0, stream>>>(Wo, wo_hiT, wo_loT);
  hipMemsetAsync(rsum, 0, 65536 * sizeof(float), stream);

  proj_gemm<<<dim3(8, 32, 3), 256, 0, stream>>>(
      qa_hi, qa_lo, ka_hi, ka_lo, va_hi, va_lo,
      wq_hiT, wq_loT, wk_hiT, wk_loT, wv_hiT, wv_loT,
      bq, bk, bv, qh, kh, vT);
  score_exp<<<dim3(16, 16, 32), 256, 0, stream>>>(qh, kh, mask, weights, rsum);
  pv_norm<<<dim3(16, 32), 256, 0, stream>>>(weights, vT, rsum, ctxB);
  out_gemm<<<dim3(8, 32), 256, 0, stream>>>(ctxB, wo_hiT, bo, out0);
}

// Round 2
// 1055.584 us; speedup vs baseline: 1.3544x; 1.1173x over previous
//
#include <hip/hip_runtime.h>
#include <hip/hip_bf16.h>

#define S_LEN 2048
#define DMODEL 1024
#define NH 16
#define DHEAD 64
#define M_TOT 4096  // B*S

typedef __attribute__((ext_vector_type(8))) short bf16x8;
typedef __attribute__((ext_vector_type(4))) float f32x4;

__device__ __forceinline__ short f2bf(float x) {
  __hip_bfloat16 h = __float2bfloat16(x);
  short s; __builtin_memcpy(&s, &h, 2); return s;
}
__device__ __forceinline__ float bf2f(short s) {
  __hip_bfloat16 h; __builtin_memcpy(&h, &s, 2);
  return __bfloat162float(h);
}

// async global->LDS copy, 16B per lane (global_load_lds_dwordx4)
__device__ __forceinline__ void async16(const short* g, short* l) {
  __builtin_amdgcn_global_load_lds(
      (const __attribute__((address_space(1))) unsigned int*)g,
      (__attribute__((address_space(3))) unsigned int*)l, 16, 0, 0);
}

// stage a 128x32 bf16 tile from row-major [*][DMODEL] src into linear LDS
__device__ __forceinline__ void stage_tile(const short* __restrict__ src, int row0,
                                           int k0, short* lds, int t) {
  const int r = t >> 2, c = (t & 3) << 3;
  async16(src + (size_t)(row0 + r) * DMODEL + k0 + c, lds + t * 8);
  async16(src + (size_t)(row0 + 64 + r) * DMODEL + k0 + c, lds + 2048 + t * 8);
}

// ---------------- elementwise: fp32 -> (hi, lo) bf16 split ----------------
__global__ void split_cvt(const float* __restrict__ src, short* __restrict__ hi,
                          short* __restrict__ lo, int n4) {
  int i = blockIdx.x * blockDim.x + threadIdx.x;
  if (i >= n4) return;
  float4 x = reinterpret_cast<const float4*>(src)[i];
  short4 h, l;
  h.x = f2bf(x.x); h.y = f2bf(x.y); h.z = f2bf(x.z); h.w = f2bf(x.w);
  l.x = f2bf(x.x - bf2f(h.x)); l.y = f2bf(x.y - bf2f(h.y));
  l.z = f2bf(x.z - bf2f(h.z)); l.w = f2bf(x.w - bf2f(h.w));
  reinterpret_cast<short4*>(hi)[i] = h;
  reinterpret_cast<short4*>(lo)[i] = l;
}

// ---------------- W (k x n fp32) -> hiT/loT (n x k bf16) ----------------
__global__ void transpose_split_w(const float* __restrict__ W,
                                  short* __restrict__ hiT, short* __restrict__ loT) {
  __shared__ float t[32][33];
  int tx = threadIdx.x;
  int kb = blockIdx.y * 32;
  int nb = blockIdx.x * 32;
  for (int ty = threadIdx.y; ty < 32; ty += 8)
    t[ty][tx] = W[(size_t)(kb + ty) * DMODEL + nb + tx];
  __syncthreads();
  for (int ty = threadIdx.y; ty < 32; ty += 8) {
    float x = t[tx][ty];
    short hv = f2bf(x);
    hiT[(size_t)(nb + ty) * DMODEL + kb + tx] = hv;
    loT[(size_t)(nb + ty) * DMODEL + kb + tx] = f2bf(x - bf2f(hv));
  }
}

// ---------------- QKV projection GEMM (split bf16, fused 3-term MFMA) ----
__launch_bounds__(256)
__global__ void proj_gemm(
    const short* __restrict__ qa_hi, const short* __restrict__ qa_lo,
    const short* __restrict__ ka_hi, const short* __restrict__ ka_lo,
    const short* __restrict__ va_hi, const short* __restrict__ va_lo,
    const short* __restrict__ wq_hiT, const short* __restrict__ wq_loT,
    const short* __restrict__ wk_hiT, const short* __restrict__ wk_loT,
    const short* __restrict__ wv_hiT, const short* __restrict__ wv_loT,
    const float* __restrict__ bq, const float* __restrict__ bk,
    const float* __restrict__ bv,
    short* __restrict__ qh, short* __restrict__ kh, short* __restrict__ vT) {
  const int which = blockIdx.z;
  const short* Ahi = (which == 0) ? qa_hi : (which == 1) ? ka_hi : va_hi;
  const short* Alo = (which == 0) ? qa_lo : (which == 1) ? ka_lo : va_lo;
  const short* Bhi = (which == 0) ? wq_hiT : (which == 1) ? wk_hiT : wv_hiT;
  const short* Blo = (which == 0) ? wq_loT : (which == 1) ? wk_loT : wv_loT;
  const float* bias = (which == 0) ? bq : (which == 1) ? bk : bv;

  const int m0 = blockIdx.y * 128, n0 = blockIdx.x * 128;
  const int t = threadIdx.x;
  const int lane = t & 63, wave = t >> 6;
  const int wm = (wave >> 1) * 64, wn = (wave & 1) * 64;
  const int lm = lane & 15, quad = lane >> 4;

  __shared__ short sAh[128 * 32], sAl[128 * 32];
  __shared__ short sBh[128 * 32], sBl[128 * 32];

  f32x4 acc[4][4];
#pragma unroll
  for (int i = 0; i < 4; i++)
#pragma unroll
    for (int j = 0; j < 4; j++) acc[i][j] = (f32x4){0.f, 0.f, 0.f, 0.f};

  for (int k0 = 0; k0 < DMODEL; k0 += 32) {
    stage_tile(Ahi, m0, k0, sAh, t);
    stage_tile(Alo, m0, k0, sAl, t);
    stage_tile(Bhi, n0, k0, sBh, t);
    stage_tile(Blo, n0, k0, sBl, t);
    __syncthreads();

    bf16x8 ah[4], al[4], bh[4], bl[4];
#pragma unroll
    for (int i = 0; i < 4; i++) {
      ah[i] = *reinterpret_cast<const bf16x8*>(sAh + (wm + i * 16 + lm) * 32 + quad * 8);
      al[i] = *reinterpret_cast<const bf16x8*>(sAl + (wm + i * 16 + lm) * 32 + quad * 8);
    }
#pragma unroll
    for (int j = 0; j < 4; j++) {
      bh[j] = *reinterpret_cast<const bf16x8*>(sBh + (wn + j * 16 + lm) * 32 + quad * 8);
      bl[j] = *reinterpret_cast<const bf16x8*>(sBl + (wn + j * 16 + lm) * 32 + quad * 8);
    }
#pragma unroll
    for (int i = 0; i < 4; i++)
#pragma unroll
      for (int j = 0; j < 4; j++) {
        acc[i][j] = __builtin_amdgcn_mfma_f32_16x16x32_bf16(ah[i], bh[j], acc[i][j], 0, 0, 0);
        acc[i][j] = __builtin_amdgcn_mfma_f32_16x16x32_bf16(ah[i], bl[j], acc[i][j], 0, 0, 0);
        acc[i][j] = __builtin_amdgcn_mfma_f32_16x16x32_bf16(al[i], bh[j], acc[i][j], 0, 0, 0);
      }
    __syncthreads();
  }

#pragma unroll
  for (int j = 0; j < 4; j++) {
    const int col = n0 + wn + j * 16 + lm;
    const float bb = bias[col];
    const int hh = col >> 6, dd = col & 63;
#pragma unroll
    for (int i = 0; i < 4; i++) {
#pragma unroll
      for (int r = 0; r < 4; r++) {
        const int row = m0 + wm + i * 16 + quad * 4 + r;
        const int bidx = row >> 11, ss = row & 2047;
        const float v = acc[i][j][r] + bb;
        if (which < 2) {
          short* dst = (which == 0) ? qh : kh;
          dst[(((size_t)(bidx * NH + hh) * S_LEN) + ss) * DHEAD + dd] = f2bf(v);
        } else {
          vT[(((size_t)(bidx * NH + hh) * DHEAD) + dd) * S_LEN + ss] = f2bf(v);
        }
      }
    }
  }
}

// ---------------- pass A: exp-rowsums of scores (no weight writes) -------
// grid (16 m-tiles, 32 bh), 256 thr. Each wave owns 32 rows exclusively ->
// direct rsum stores, no atomics, no memset needed.
__launch_bounds__(256)
__global__ void row_sums(const short* __restrict__ qh, const short* __restrict__ kh,
                         const float* __restrict__ mask, float* __restrict__ rsum) {
  const int bh = blockIdx.y;
  const int m0 = blockIdx.x * 128;
  const int lane = threadIdx.x & 63, wave = threadIdx.x >> 6;
  const int lm = lane & 15, quad = lane >> 4;
  const int wrow = m0 + wave * 32;
  const short* qb = qh + (size_t)bh * S_LEN * DHEAD;
  const short* kb = kh + (size_t)bh * S_LEN * DHEAD;
  const float* mrow = mask + (size_t)(bh >> 4) * S_LEN;

  bf16x8 aq[2][2];
#pragma unroll
  for (int i = 0; i < 2; i++)
#pragma unroll
    for (int k = 0; k < 2; k++)
      aq[i][k] = *reinterpret_cast<const bf16x8*>(
          qb + (size_t)(wrow + i * 16 + lm) * DHEAD + k * 32 + quad * 8);

  float rs[2][4];
#pragma unroll
  for (int i = 0; i < 2; i++)
#pragma unroll
    for (int r = 0; r < 4; r++) rs[i][r] = 0.f;

  for (int n = 0; n < S_LEN; n += 64) {
    bf16x8 bk[4][2];
#pragma unroll
    for (int j = 0; j < 4; j++)
#pragma unroll
      for (int k = 0; k < 2; k++)
        bk[j][k] = *reinterpret_cast<const bf16x8*>(
            kb + (size_t)(n + j * 16 + lm) * DHEAD + k * 32 + quad * 8);
    f32x4 acc[2][4];
#pragma unroll
    for (int i = 0; i < 2; i++)
#pragma unroll
      for (int j = 0; j < 4; j++) acc[i][j] = (f32x4){0.f, 0.f, 0.f, 0.f};
#pragma unroll
    for (int k = 0; k < 2; k++)
#pragma unroll
      for (int i = 0; i < 2; i++)
#pragma unroll
        for (int j = 0; j < 4; j++)
          acc[i][j] = __builtin_amdgcn_mfma_f32_16x16x32_bf16(aq[i][k], bk[j][k], acc[i][j], 0, 0, 0);

    float msk[4];
#pragma unroll
    for (int j = 0; j < 4; j++) msk[j] = mrow[n + j * 16 + lm] * -1e9f;
#pragma unroll
    for (int i = 0; i < 2; i++)
#pragma unroll
      for (int j = 0; j < 4; j++)
#pragma unroll
        for (int r = 0; r < 4; r++)
          rs[i][r] += __expf(acc[i][j][r] * 0.125f + msk[j]);
  }
#pragma unroll
  for (int i = 0; i < 2; i++)
#pragma unroll
    for (int r = 0; r < 4; r++) {
      float v = rs[i][r];
      v += __shfl_xor(v, 1); v += __shfl_xor(v, 2);
      v += __shfl_xor(v, 4); v += __shfl_xor(v, 8);
      if (lm == 0)
        rsum[(size_t)bh * S_LEN + wrow + i * 16 + quad * 4 + r] = v;
    }
}

// ---------------- pass B: fused normalize-write + PV ---------------------
// Per 128-row block: loop 128-col chunks; QK^T -> e*rinv -> write FINAL
// weights once -> barrier -> read chunk back (L2-hot) as PV A-operand.
__launch_bounds__(256)
__global__ void attn_fused(const short* __restrict__ qh, const short* __restrict__ kh,
                           const short* __restrict__ vT, const float* __restrict__ mask,
                           const float* __restrict__ rsum,
                           float* __restrict__ wout, short* __restrict__ ctxB) {
  const int bh = blockIdx.y;
  const int m0 = blockIdx.x * 128;
  const int lane = threadIdx.x & 63, wave = threadIdx.x >> 6;
  const int wm = (wave >> 1) * 64, wn = (wave & 1) * 64, wn2 = (wave & 1) * 32;
  const int lm = lane & 15, quad = lane >> 4;
  const short* qb = qh + (size_t)bh * S_LEN * DHEAD;
  const short* kb = kh + (size_t)bh * S_LEN * DHEAD;
  const short* vb = vT + (size_t)bh * DHEAD * S_LEN;
  float* wb = wout + (size_t)bh * S_LEN * S_LEN;
  const float* mrow = mask + (size_t)(bh >> 4) * S_LEN;

  bf16x8 aq[4][2];
#pragma unroll
  for (int i = 0; i < 4; i++)
#pragma unroll
    for (int k = 0; k < 2; k++)
      aq[i][k] = *reinterpret_cast<const bf16x8*>(
          qb + (size_t)(m0 + wm + i * 16 + lm) * DHEAD + k * 32 + quad * 8);

  float rinv[4][4];
#pragma unroll
  for (int i = 0; i < 4; i++)
#pragma unroll
    for (int r = 0; r < 4; r++)
      rinv[i][r] = 1.0f / rsum[(size_t)bh * S_LEN + m0 + wm + i * 16 + quad * 4 + r];

  f32x4 ctx[4][2];
#pragma unroll
  for (int i = 0; i < 4; i++)
#pragma unroll
    for (int j = 0; j < 2; j++) ctx[i][j] = (f32x4){0.f, 0.f, 0.f, 0.f};

  for (int c = 0; c < S_LEN; c += 128) {
    // --- phase 1: scores chunk (each wave: 64x64 of the 128x128) ---
    bf16x8 bk[4][2];
#pragma unroll
    for (int j = 0; j < 4; j++)
#pragma unroll
      for (int k = 0; k < 2; k++)
        bk[j][k] = *reinterpret_cast<const bf16x8*>(
            kb + (size_t)(c + wn + j * 16 + lm) * DHEAD + k * 32 + quad * 8);
    f32x4 s[4][4];
#pragma unroll
    for (int i = 0; i < 4; i++)
#pragma unroll
      for (int j = 0; j < 4; j++) s[i][j] = (f32x4){0.f, 0.f, 0.f, 0.f};
#pragma unroll
    for (int k = 0; k < 2; k++)
#pragma unroll
      for (int i = 0; i < 4; i++)
#pragma unroll
        for (int j = 0; j < 4; j++)
          s[i][j] = __builtin_amdgcn_mfma_f32_16x16x32_bf16(aq[i][k], bk[j][k], s[i][j], 0, 0, 0);

    float msk[4];
#pragma unroll
    for (int j = 0; j < 4; j++) msk[j] = mrow[c + wn + j * 16 + lm] * -1e9f;
#pragma unroll
    for (int i = 0; i < 4; i++)
#pragma unroll
      for (int j = 0; j < 4; j++)
#pragma unroll
        for (int r = 0; r < 4; r++) {
          const int row = m0 + wm + i * 16 + quad * 4 + r;
          float e = __expf(s[i][j][r] * 0.125f + msk[j]) * rinv[i][r];
          wb[(size_t)row * S_LEN + c + wn + j * 16 + lm] = e;  // FINAL weights
        }
    __syncthreads();  // chunk writes visible block-wide (L2)

    // --- phase 2: ctx += P_chunk @ V_chunk (wave: 64 rows x 32 d-cols) ---
#pragma unroll
    for (int kk = 0; kk < 128; kk += 32) {
      bf16x8 ap[4];
#pragma unroll
      for (int i = 0; i < 4; i++) {
        const float4* p = reinterpret_cast<const float4*>(
            wb + (size_t)(m0 + wm + i * 16 + lm) * S_LEN + c + kk + quad * 8);
        float4 x0 = p[0], x1 = p[1];
        bf16x8 av;
        av[0] = f2bf(x0.x); av[1] = f2bf(x0.y); av[2] = f2bf(x0.z); av[3] = f2bf(x0.w);
        av[4] = f2bf(x1.x); av[5] = f2bf(x1.y); av[6] = f2bf(x1.z); av[7] = f2bf(x1.w);
        ap[i] = av;
      }
      bf16x8 bv[2];
#pragma unroll
      for (int j = 0; j < 2; j++)
        bv[j] = *reinterpret_cast<const bf16x8*>(
            vb + (size_t)(wn2 + j * 16 + lm) * S_LEN + c + kk + quad * 8);
#pragma unroll
      for (int i = 0; i < 4; i++)
#pragma unroll
        for (int j = 0; j < 2; j++)
          ctx[i][j] = __builtin_amdgcn_mfma_f32_16x16x32_bf16(ap[i], bv[j], ctx[i][j], 0, 0, 0);
    }
    // no second barrier: next chunk writes disjoint wb columns
  }

  const int b_ = bh >> 4, h = bh & 15;
#pragma unroll
  for (int i = 0; i < 4; i++)
#pragma unroll
    for (int j = 0; j < 2; j++)
#pragma unroll
      for (int r = 0; r < 4; r++) {
        const int ss = m0 + wm + i * 16 + quad * 4 + r;
        const int dd = wn2 + j * 16 + lm;
        ctxB[((size_t)(b_ * S_LEN + ss)) * DMODEL + h * DHEAD + dd] = f2bf(ctx[i][j][r]);
      }
}

// ---------------- output projection: out = ctx @ Wo + bo (bf16 MFMA) -----
__launch_bounds__(256)
__global__ void out_gemm(const short* __restrict__ ctxB, const short* __restrict__ woT,
                         const float* __restrict__ bo, float* __restrict__ out) {
  const int m0 = blockIdx.y * 128, n0 = blockIdx.x * 128;
  const int t = threadIdx.x;
  const int lane = t & 63, wave = t >> 6;
  const int wm = (wave >> 1) * 64, wn = (wave & 1) * 64;
  const int lm = lane & 15, quad = lane >> 4;

  __shared__ short sA[128 * 32], sB[128 * 32];

  f32x4 acc[4][4];
#pragma unroll
  for (int i = 0; i < 4; i++)
#pragma unroll
    for (int j = 0; j < 4; j++) acc[i][j] = (f32x4){0.f, 0.f, 0.f, 0.f};

  for (int k0 = 0; k0 < DMODEL; k0 += 32) {
    stage_tile(ctxB, m0, k0, sA, t);
    stage_tile(woT, n0, k0, sB, t);
    __syncthreads();

    bf16x8 a[4], b[4];
#pragma unroll
    for (int i = 0; i < 4; i++)
      a[i] = *reinterpret_cast<const bf16x8*>(sA + (wm + i * 16 + lm) * 32 + quad * 8);
#pragma unroll
    for (int j = 0; j < 4; j++)
      b[j] = *reinterpret_cast<const bf16x8*>(sB + (wn + j * 16 + lm) * 32 + quad * 8);
#pragma unroll
    for (int i = 0; i < 4; i++)
#pragma unroll
      for (int j = 0; j < 4; j++)
        acc[i][j] = __builtin_amdgcn_mfma_f32_16x16x32_bf16(a[i], b[j], acc[i][j], 0, 0, 0);
    __syncthreads();
  }

#pragma unroll
  for (int j = 0; j < 4; j++) {
    const int col = n0 + wn + j * 16 + lm;
    const float bb = bo[col];
#pragma unroll
    for (int i = 0; i < 4; i++)
#pragma unroll
      for (int r = 0; r < 4; r++) {
        const int row = m0 + wm + i * 16 + quad * 4 + r;
        out[(size_t)row * DMODEL + col] = acc[i][j][r] + bb;
      }
  }
}

extern "C" void kernel_launch(void* const* d_in, const int* in_sizes, int n_in,
                              void* d_out, int out_size, void* d_ws, size_t ws_size,
                              hipStream_t stream) {
  const float* Q = (const float*)d_in[0];
  const float* K = (const float*)d_in[1];
  const float* V = (const float*)d_in[2];
  const float* mask = (const float*)d_in[3];
  const float* Wq = (const float*)d_in[4];
  const float* bq = (const float*)d_in[5];
  const float* Wk = (const float*)d_in[6];
  const float* bk = (const float*)d_in[7];
  const float* Wv = (const float*)d_in[8];
  const float* bv = (const float*)d_in[9];
  const float* Wo = (const float*)d_in[10];
  const float* bo = (const float*)d_in[11];

  float* out0 = (float*)d_out;                                   // (B,S,DM)
  float* weights = (float*)d_out + (size_t)M_TOT * DMODEL;       // (B,H,S,S)

  char* w = (char*)d_ws;
  const size_t MB = 1ull << 20;
  short* qh = (short*)(w + 0 * MB);        // 8 MB  [b][h][s][d] bf16
  short* kh = (short*)(w + 8 * MB);        // 8 MB  [b][h][s][d]
  short* vT = (short*)(w + 16 * MB);       // 8 MB  [b][h][d][s]
  short* ctxB = (short*)(w + 24 * MB);     // 8 MB  [b*s][dm]
  float* rsum = (float*)(w + 32 * MB);     // 256 KB (pad to 1 MB)
  short* wq_hiT = (short*)(w + 33 * MB);
  short* wq_loT = (short*)(w + 35 * MB);
  short* wk_hiT = (short*)(w + 37 * MB);
  short* wk_loT = (short*)(w + 39 * MB);
  short* wv_hiT = (short*)(w + 41 * MB);
  short* wv_loT = (short*)(w + 43 * MB);
  short* wo_hiT = (short*)(w + 45 * MB);
  short* wo_loT = (short*)(w + 47 * MB);
  short* qa_hi = (short*)(w + 49 * MB);
  short* qa_lo = (short*)(w + 57 * MB);
  short* ka_hi = (short*)(w + 65 * MB);
  short* ka_lo = (short*)(w + 73 * MB);
  short* va_hi = (short*)(w + 81 * MB);
  short* va_lo = (short*)(w + 89 * MB);    // total footprint: 97 MB

  const int n4 = M_TOT * DMODEL / 4;  // 1,048,576
  split_cvt<<<dim3(n4 / 256), 256, 0, stream>>>(Q, qa_hi, qa_lo, n4);
  split_cvt<<<dim3(n4 / 256), 256, 0, stream>>>(K, ka_hi, ka_lo, n4);
  split_cvt<<<dim3(n4 / 256), 256, 0, stream>>>(V, va_hi, va_lo, n4);
  transpose_split_w<<<dim3(32, 32), dim3(32, 8), 0, stream>>>(Wq, wq_hiT, wq_loT);
  transpose_split_w<<<dim3(32, 32), dim3(32, 8), 0, stream>>>(Wk, wk_hiT, wk_loT);
  transpose_split_w<<<dim3(32, 32), dim3(32, 8), 0, stream>>>(Wv, wv_hiT, wv_loT);
  transpose_split_w<<<dim3(32, 32), dim3(32, 8), 0, stream>>>(Wo, wo_hiT, wo_loT);

  proj_gemm<<<dim3(8, 32, 3), 256, 0, stream>>>(
      qa_hi, qa_lo, ka_hi, ka_lo, va_hi, va_lo,
      wq_hiT, wq_loT, wk_hiT, wk_loT, wv_hiT, wv_loT,
      bq, bk, bv, qh, kh, vT);
  row_sums<<<dim3(16, 32), 256, 0, stream>>>(qh, kh, mask, rsum);
  attn_fused<<<dim3(16, 32), 256, 0, stream>>>(qh, kh, vT, mask, rsum, weights, ctxB);
  out_gemm<<<dim3(8, 32), 256, 0, stream>>>(ctxB, wo_hiT, bo, out0);
}